// Round 6
// baseline (365.408 us; speedup 1.0000x reference)
//
#include <hip/hip_runtime.h>
#include <cmath>

// GCN 2-layer forward on MI355X — round 6: src-sorted neighbor lists for L2-resident
// gather streams (all waves sweep src space in roughly the same order).
// Pipeline: bcount -> bscan -> bscatter(packed) -> bbuild(+per-node src sort in LDS) ->
//           gemm1_mfma(x@W1 -> bf16) -> agg128 (bias+selfloop+relu -> bf16 h1) ->
//           gemm2_mfma(h1@W2 -> bf16) -> agg64+log_softmax fused -> done.

#define THREADS 256
#define BSHIFT 8                      // 256 nodes per bucket
#define MAXB 512                      // >= ceil(N / 256)
#define BCAP 8192                     // max edges per bucket staged in LDS (avg ~4092)

__device__ __forceinline__ unsigned short f2bf(float f) {
    union { float f; unsigned u; } v; v.f = f;
    unsigned r = v.u + 0x7FFFu + ((v.u >> 16) & 1u);   // round-nearest-even
    return (unsigned short)(r >> 16);
}
__device__ __forceinline__ float bf_lo(unsigned u) {
    union { unsigned u; float f; } v; v.u = u << 16; return v.f;
}
__device__ __forceinline__ float bf_hi(unsigned u) {
    union { unsigned u; float f; } v; v.u = u & 0xFFFF0000u; return v.f;
}

// ---- bucket count: LDS histogram, flush once per block ----
__global__ __launch_bounds__(256) void k_bcount(const int* __restrict__ dst, int E, int B,
                                                int* __restrict__ bcnt) {
    __shared__ int lc[MAXB];
    for (int i = threadIdx.x; i < MAXB; i += 256) lc[i] = 0;
    __syncthreads();
    for (int e = blockIdx.x * blockDim.x + threadIdx.x; e < E; e += gridDim.x * blockDim.x)
        atomicAdd(&lc[dst[e] >> BSHIFT], 1);
    __syncthreads();
    for (int b = threadIdx.x; b < B; b += 256)
        if (lc[b]) atomicAdd(&bcnt[b], lc[b]);
}

// ---- exclusive scan of bcnt[B] -> boff[B+1], single block of 512 ----
__global__ void k_bscan(const int* __restrict__ bcnt, int B, int* __restrict__ boff) {
    __shared__ int sh[MAXB];
    const int t = threadIdx.x;
    int v = (t < B) ? bcnt[t] : 0;
    sh[t] = v; __syncthreads();
    for (int o = 1; o < MAXB; o <<= 1) {
        int add = (t >= o) ? sh[t - o] : 0;
        __syncthreads();
        sh[t] += add;
        __syncthreads();
    }
    if (t < B) boff[t] = sh[t] - v;
    if (t == B - 1) boff[B] = sh[t];
}

// ---- scatter edges into bucket-contiguous packed records (loc<<24 | src) ----
__global__ __launch_bounds__(256) void k_bscatter(const int* __restrict__ src,
                                                  const int* __restrict__ dst, int E, int B,
                                                  const int* __restrict__ boff,
                                                  int* __restrict__ bfill,
                                                  unsigned* __restrict__ pairs) {
    __shared__ int lc[MAXB];     // per-block bucket count, then per-bucket rank
    __shared__ int lbase[MAXB];  // global reservation base within bucket
    const int tid = threadIdx.x;
    const int e0 = blockIdx.x * 8192;
    for (int i = tid; i < MAXB; i += 256) lc[i] = 0;
    __syncthreads();
#pragma unroll
    for (int k = 0; k < 32; k++) {
        int e = e0 + k * 256 + tid;
        if (e < E) atomicAdd(&lc[dst[e] >> BSHIFT], 1);
    }
    __syncthreads();
    for (int b = tid; b < B; b += 256)
        lbase[b] = lc[b] ? atomicAdd(&bfill[b], lc[b]) : 0;
    __syncthreads();
    for (int i = tid; i < MAXB; i += 256) lc[i] = 0;  // reuse as rank
    __syncthreads();
#pragma unroll
    for (int k = 0; k < 32; k++) {
        int e = e0 + k * 256 + tid;
        if (e < E) {
            int s = src[e], d = dst[e];
            int b = d >> BSHIFT;
            int r = atomicAdd(&lc[b], 1);
            pairs[(size_t)boff[b] + lbase[b] + r] =
                ((unsigned)(d & 255) << 24) | (unsigned)s;   // src < 2^24
        }
    }
}

// ---- per-bucket CSR build: one block per bucket; all scatter is LDS-local.
//      Each node's neighbor segment is sorted by src id so that the agg kernels
//      sweep the gather source in ascending address order (L2 locality).
__global__ __launch_bounds__(256) void k_bbuild(const unsigned* __restrict__ pairs,
                                                const int* __restrict__ boff, int N,
                                                int* __restrict__ deg,
                                                float* __restrict__ dinv,
                                                int* __restrict__ rowptr,
                                                int* __restrict__ csr_src) {
    __shared__ int ldeg[256], lex[256], lrank[256];
    __shared__ int lcsr[BCAP];
    const int b = blockIdx.x, tid = threadIdx.x;
    const int node0 = b << BSHIFT;
    const int base = boff[b];
    const int cnt_e = boff[b + 1] - base;
    ldeg[tid] = 0;
    __syncthreads();
    for (int e = tid; e < cnt_e; e += 256)
        atomicAdd(&ldeg[pairs[base + e] >> 24], 1);
    __syncthreads();
    int v = ldeg[tid];
    lex[tid] = v; __syncthreads();
    for (int o = 1; o < 256; o <<= 1) {
        int add = (tid >= o) ? lex[tid - o] : 0;
        __syncthreads();
        lex[tid] += add;
        __syncthreads();
    }
    const int excl = lex[tid] - v;   // bucket-relative start of this node's segment
    if (node0 + tid < N) {
        deg[node0 + tid] = v;
        dinv[node0 + tid] = rsqrtf((float)(v + 1));
        rowptr[node0 + tid] = base + excl;
    }
    __syncthreads();
    lex[tid] = excl;
    lrank[tid] = 0;
    __syncthreads();
    if (cnt_e <= BCAP) {
        // stage into LDS (arrival order within each node's segment)
        for (int e = tid; e < cnt_e; e += 256) {
            unsigned p = pairs[base + e];
            int loc = p >> 24;
            int r = atomicAdd(&lrank[loc], 1);
            lcsr[lex[loc] + r] = (int)(p & 0xFFFFFFu);
        }
        __syncthreads();
        // insertion-sort each node's segment by src id (one thread per node)
        for (int a = 1; a < v; a++) {
            int key = lcsr[excl + a];
            int c = a - 1;
            while (c >= 0 && lcsr[excl + c] > key) { lcsr[excl + c + 1] = lcsr[excl + c]; c--; }
            lcsr[excl + c + 1] = key;
        }
        __syncthreads();
        // coalesced write-out
        for (int e = tid; e < cnt_e; e += 256) csr_src[base + e] = lcsr[e];
    } else {
        // fallback (should not trigger at E/B ~ 4k): unsorted direct scatter
        for (int e = tid; e < cnt_e; e += 256) {
            unsigned p = pairs[base + e];
            int loc = p >> 24;
            int r = atomicAdd(&lrank[loc], 1);
            csr_src[base + lex[loc] + r] = (int)(p & 0xFFFFFFu);
        }
    }
}

// Wt1[n][k] = bf16(W1[k][n]) (128x128), Wt2[n][k] = bf16(W2[k][n]) (64x128)
__global__ void k_castW(const float* __restrict__ W1, const float* __restrict__ W2,
                        unsigned short* __restrict__ Wt1, unsigned short* __restrict__ Wt2) {
    int idx = blockIdx.x * blockDim.x + threadIdx.x;
    if (idx < 16384) {
        int n = idx >> 7, k = idx & 127;
        Wt1[idx] = f2bf(W1[k * 128 + n]);
    } else if (idx < 16384 + 8192) {
        int t = idx - 16384;
        int n = t >> 7, k = t & 127;
        Wt2[t] = f2bf(W2[k * 64 + n]);
    }
}

// C[M x NC](bf16) = A[M x 128] @ Wt^T, Wt is [NC x 128] bf16 (pre-transposed W).
typedef __attribute__((ext_vector_type(8))) short bf16x8;
typedef __attribute__((ext_vector_type(4))) float f32x4;

template <int NC, bool A_BF16>
__global__ __launch_bounds__(256) void k_gemm_mfma(const void* __restrict__ Av,
                                                   const unsigned short* __restrict__ Wt,
                                                   unsigned short* __restrict__ Out, int M) {
    constexpr int KP = 136;                 // padded k-stride
    __shared__ __align__(16) short As[64 * KP];
    __shared__ __align__(16) short Bs[NC * KP];
    const int tid = threadIdx.x;
    const int row0 = blockIdx.x * 64;

    if (A_BF16) {
        const unsigned short* A = (const unsigned short*)Av;
#pragma unroll
        for (int q = 0; q < 4; q++) {
            int f = tid + 256 * q;
            int r = f >> 4, c = (f & 15) * 8;
            uint4 v = make_uint4(0, 0, 0, 0);
            if (row0 + r < M) v = *(const uint4*)&A[(size_t)(row0 + r) * 128 + c];
            *(uint4*)&As[r * KP + c] = v;
        }
    } else {
        const float* A = (const float*)Av;
#pragma unroll
        for (int q = 0; q < 8; q++) {
            int f = tid + 256 * q;
            int r = f >> 5, c = (f & 31) * 4;
            float4 v = make_float4(0.f, 0.f, 0.f, 0.f);
            if (row0 + r < M) v = *(const float4*)&A[(size_t)(row0 + r) * 128 + c];
            ushort4 o;
            o.x = f2bf(v.x); o.y = f2bf(v.y); o.z = f2bf(v.z); o.w = f2bf(v.w);
            *(ushort4*)&As[r * KP + c] = o;
        }
    }
    for (int f = tid; f < NC * 16; f += 256) {
        int n = f >> 4, c = (f & 15) * 8;
        *(uint4*)&Bs[n * KP + c] = *(const uint4*)&Wt[n * 128 + c];
    }
    __syncthreads();

    const int wave = tid >> 6, lane = tid & 63;
    const int m = lane & 15, quad = lane >> 4;
    constexpr int CT = NC / 16;
    f32x4 acc[CT] = {};
    const short* arow = &As[(16 * wave + m) * KP + quad * 8];
    const short* brow = &Bs[m * KP + quad * 8];
#pragma unroll
    for (int k0 = 0; k0 < 128; k0 += 32) {
        bf16x8 a = *(const bf16x8*)&arow[k0];
#pragma unroll
        for (int c = 0; c < CT; c++) {
            bf16x8 b = *(const bf16x8*)&brow[(size_t)c * 16 * KP + k0];
            acc[c] = __builtin_amdgcn_mfma_f32_16x16x32_bf16(a, b, acc[c], 0, 0, 0);
        }
    }

    __syncthreads();
    short* Cs = As;
#pragma unroll
    for (int c = 0; c < CT; c++)
#pragma unroll
        for (int r = 0; r < 4; r++)
            Cs[(16 * wave + quad * 4 + r) * NC + 16 * c + m] = (short)f2bf(acc[c][r]);
    __syncthreads();
    for (int f = tid; f < 64 * NC / 8; f += 256) {
        int r = f / (NC / 8), c = (f % (NC / 8)) * 8;
        if (row0 + r < M)
            *(uint4*)&Out[(size_t)(row0 + r) * NC + c] = *(const uint4*)&Cs[r * NC + c];
    }
}

// Aggregate 128-wide bf16 rows. One wave per node; lane covers cols {2l, 2l+1}.
// Neighbor lists are src-sorted -> resident waves sweep xw in ascending order.
__global__ __launch_bounds__(256) void k_agg128b(const int* __restrict__ csr_src,
                                                 const int* __restrict__ rowptr,
                                                 const int* __restrict__ cnt,
                                                 const float* __restrict__ dinv,
                                                 const unsigned* __restrict__ xw,
                                                 const float* __restrict__ bias,
                                                 unsigned* __restrict__ h1, int N) {
    const int lane = threadIdx.x & 63;
    const int i = (blockIdx.x * blockDim.x + threadIdx.x) >> 6;
    if (i >= N) return;
    const float di = dinv[i];
    unsigned u = xw[(size_t)i * 64 + lane];
    float acc0 = di * di * bf_lo(u);
    float acc1 = di * di * bf_hi(u);
    const int start = rowptr[i], cn = cnt[i];
    int j = 0;
    for (; j + 8 <= cn; j += 8) {
        int s[8]; unsigned uu[8]; float w[8];
#pragma unroll
        for (int k = 0; k < 8; k++) s[k] = csr_src[start + j + k];   // wave-uniform -> s_load
#pragma unroll
        for (int k = 0; k < 8; k++) uu[k] = xw[(size_t)s[k] * 64 + lane];
#pragma unroll
        for (int k = 0; k < 8; k++) w[k] = dinv[s[k]] * di;
#pragma unroll
        for (int k = 0; k < 8; k++) {
            acc0 += w[k] * bf_lo(uu[k]);
            acc1 += w[k] * bf_hi(uu[k]);
        }
    }
    for (; j < cn; j++) {
        int s0 = csr_src[start + j];
        float w0 = dinv[s0] * di;
        unsigned u0 = xw[(size_t)s0 * 64 + lane];
        acc0 += w0 * bf_lo(u0); acc1 += w0 * bf_hi(u0);
    }
    float2 b = *(const float2*)&bias[2 * lane];
    float r0 = fmaxf(acc0 + b.x, 0.f);    // ReLU folded (layer-1 epilogue)
    float r1 = fmaxf(acc1 + b.y, 0.f);
    h1[(size_t)i * 64 + lane] = (unsigned)f2bf(r0) | ((unsigned)f2bf(r1) << 16);
}

// Aggregate 64-wide bf16 rows; half-wave per edge stream, 4-deep unroll per half.
// log_softmax fused into the epilogue.
__global__ __launch_bounds__(256) void k_agg64b(const int* __restrict__ csr_src,
                                                const int* __restrict__ rowptr,
                                                const int* __restrict__ cnt,
                                                const float* __restrict__ dinv,
                                                const unsigned* __restrict__ xw,
                                                const float* __restrict__ bias,
                                                float* __restrict__ out, int N) {
    const int lane = threadIdx.x & 63;
    const int i = (blockIdx.x * blockDim.x + threadIdx.x) >> 6;
    if (i >= N) return;
    const int h = lane >> 5, sl = lane & 31;
    const float di = dinv[i];
    float acc0 = 0.f, acc1 = 0.f;
    if (h == 0) {
        unsigned u = xw[(size_t)i * 32 + sl];
        acc0 = di * di * bf_lo(u);
        acc1 = di * di * bf_hi(u);
    }
    const int start = rowptr[i], cn = cnt[i];
    int e = h;
    for (; e + 6 < cn; e += 8) {          // each half: edges e, e+2, e+4, e+6
        int s[4]; unsigned uu[4]; float w[4];
#pragma unroll
        for (int k = 0; k < 4; k++) s[k] = csr_src[start + e + 2 * k];
#pragma unroll
        for (int k = 0; k < 4; k++) uu[k] = xw[(size_t)s[k] * 32 + sl];
#pragma unroll
        for (int k = 0; k < 4; k++) w[k] = dinv[s[k]] * di;
#pragma unroll
        for (int k = 0; k < 4; k++) {
            acc0 += w[k] * bf_lo(uu[k]);
            acc1 += w[k] * bf_hi(uu[k]);
        }
    }
    for (; e < cn; e += 2) {
        int s0 = csr_src[start + e];
        float w0 = dinv[s0] * di;
        unsigned u0 = xw[(size_t)s0 * 32 + sl];
        acc0 += w0 * bf_lo(u0); acc1 += w0 * bf_hi(u0);
    }
    acc0 += __shfl_xor(acc0, 32);         // both halves now hold full sums
    acc1 += __shfl_xor(acc1, 32);
    float2 b = *(const float2*)&bias[2 * sl];
    float v0 = acc0 + b.x, v1 = acc1 + b.y;
    float m = fmaxf(v0, v1);
#pragma unroll
    for (int o = 16; o > 0; o >>= 1) m = fmaxf(m, __shfl_xor(m, o));
    float s2 = expf(v0 - m) + expf(v1 - m);
#pragma unroll
    for (int o = 16; o > 0; o >>= 1) s2 += __shfl_xor(s2, o);
    float ls = m + logf(s2);
    if (h == 0)
        *(float2*)&out[(size_t)i * 64 + 2 * sl] = make_float2(v0 - ls, v1 - ls);
}

extern "C" void kernel_launch(void* const* d_in, const int* in_sizes, int n_in,
                              void* d_out, int out_size, void* d_ws, size_t ws_size,
                              hipStream_t stream) {
    const float* x  = (const float*)d_in[0];
    const int*   ei = (const int*)d_in[1];
    const float* W1 = (const float*)d_in[2];
    const float* b1 = (const float*)d_in[3];
    const float* W2 = (const float*)d_in[4];
    const float* b2 = (const float*)d_in[5];

    const int N = in_sizes[0] / 128;   // 100000
    const int E = in_sizes[1] / 2;     // 1600000
    const int* src = ei;
    const int* dst = ei + E;
    const int B = (N + 255) >> BSHIFT; // 391 buckets

    char* ws = (char*)d_ws;
    size_t off = 0;
    auto alloc = [&](size_t bytes) {
        void* p = ws + off;
        off += (bytes + 255) & ~(size_t)255;
        return p;
    };
    int*            bcnt    = (int*)alloc(MAXB * 4 * 2);    // bcnt + bfill adjacent
    int*            bfill   = bcnt + MAXB;
    int*            boff    = (int*)alloc((MAXB + 1) * 4);
    int*            deg     = (int*)alloc((size_t)N * 4);
    float*          dinv    = (float*)alloc((size_t)N * 4);
    int*            rowptr  = (int*)alloc((size_t)N * 4);
    int*            csr_src = (int*)alloc((size_t)E * 4);
    unsigned*       pairs   = (unsigned*)alloc((size_t)E * 4);
    unsigned short* Wt1     = (unsigned short*)alloc(128 * 128 * 2);
    unsigned short* Wt2     = (unsigned short*)alloc(64 * 128 * 2);
    unsigned short* xw1     = (unsigned short*)alloc((size_t)N * 128 * 2);  // bf16; reused as hw2
    unsigned short* h1      = (unsigned short*)alloc((size_t)N * 128 * 2);  // bf16
    unsigned short* hw2     = xw1;
    float*          out     = (float*)d_out;

    hipMemsetAsync(bcnt, 0, MAXB * 4 * 2, stream);

    // CSR build (bucketed, src-sorted neighbor lists)
    k_bcount<<<512, THREADS, 0, stream>>>(dst, E, B, bcnt);
    k_bscan<<<1, MAXB, 0, stream>>>(bcnt, B, boff);
    k_bscatter<<<(E + 8191) / 8192, THREADS, 0, stream>>>(src, dst, E, B, boff, bfill, pairs);
    k_bbuild<<<B, THREADS, 0, stream>>>(pairs, boff, N, deg, dinv, rowptr, csr_src);

    k_castW<<<96, THREADS, 0, stream>>>(W1, W2, Wt1, Wt2);

    // Layer 1
    k_gemm_mfma<128, false><<<(N + 63) / 64, THREADS, 0, stream>>>(x, Wt1, xw1, N);
    k_agg128b<<<(N * 64 + THREADS - 1) / THREADS, THREADS, 0, stream>>>(
        csr_src, rowptr, deg, dinv, (const unsigned*)xw1, b1, (unsigned*)h1, N);

    // Layer 2 (+ fused log_softmax)
    k_gemm_mfma<64, true><<<(N + 63) / 64, THREADS, 0, stream>>>(h1, Wt2, hw2, N);
    k_agg64b<<<(N * 64 + THREADS - 1) / THREADS, THREADS, 0, stream>>>(
        csr_src, rowptr, deg, dinv, (const unsigned*)hw2, b2, out, N);
}

// Round 7
// 351.049 us; speedup vs baseline: 1.0409x; 1.0409x over previous
//
#include <hip/hip_runtime.h>
#include <cmath>

// GCN 2-layer forward on MI355X — round 7: consolidation.
// - bbuild reverted to round-5 (LDS sort was -38us regression, FETCH unchanged)
// - tables pre-scaled by dinv[src] in GEMM epilogue -> agg is pure gather-sum
// - nontemporal csr loads; castW fused into bscan.
// Pipeline: bcount -> bscan(+castW) -> bscatter(packed) -> bbuild ->
//           gemm1_mfma(x@W1, row-scaled, bf16) -> agg128 (sum, then di*acc+bias, relu) ->
//           gemm2_mfma(h1@W2, row-scaled, bf16) -> agg64 + fused log_softmax.

#define THREADS 256
#define BSHIFT 8                      // 256 nodes per bucket
#define MAXB 512                      // >= ceil(N / 256)

__device__ __forceinline__ unsigned short f2bf(float f) {
    union { float f; unsigned u; } v; v.f = f;
    unsigned r = v.u + 0x7FFFu + ((v.u >> 16) & 1u);   // round-nearest-even
    return (unsigned short)(r >> 16);
}
__device__ __forceinline__ float bf_lo(unsigned u) {
    union { unsigned u; float f; } v; v.u = u << 16; return v.f;
}
__device__ __forceinline__ float bf_hi(unsigned u) {
    union { unsigned u; float f; } v; v.u = u & 0xFFFF0000u; return v.f;
}

// ---- bucket count: LDS histogram, flush once per block ----
__global__ __launch_bounds__(256) void k_bcount(const int* __restrict__ dst, int E, int B,
                                                int* __restrict__ bcnt) {
    __shared__ int lc[MAXB];
    for (int i = threadIdx.x; i < MAXB; i += 256) lc[i] = 0;
    __syncthreads();
    for (int e = blockIdx.x * blockDim.x + threadIdx.x; e < E; e += gridDim.x * blockDim.x)
        atomicAdd(&lc[dst[e] >> BSHIFT], 1);
    __syncthreads();
    for (int b = threadIdx.x; b < B; b += 256)
        if (lc[b]) atomicAdd(&bcnt[b], lc[b]);
}

// ---- block 0: exclusive scan of bcnt[B] -> boff[B+1]; blocks 1..: cast W -> bf16^T ----
__global__ __launch_bounds__(512) void k_bscan(const int* __restrict__ bcnt, int B,
                                               int* __restrict__ boff,
                                               const float* __restrict__ W1,
                                               const float* __restrict__ W2,
                                               unsigned short* __restrict__ Wt1,
                                               unsigned short* __restrict__ Wt2) {
    if (blockIdx.x == 0) {
        __shared__ int sh[MAXB];
        const int t = threadIdx.x;
        int v = (t < B) ? bcnt[t] : 0;
        sh[t] = v; __syncthreads();
        for (int o = 1; o < MAXB; o <<= 1) {
            int add = (t >= o) ? sh[t - o] : 0;
            __syncthreads();
            sh[t] += add;
            __syncthreads();
        }
        if (t < B) boff[t] = sh[t] - v;
        if (t == B - 1) boff[B] = sh[t];
    } else {
        int idx = (blockIdx.x - 1) * 512 + threadIdx.x;   // 0..24575
        if (idx < 16384) {
            int n = idx >> 7, k = idx & 127;
            Wt1[idx] = f2bf(W1[k * 128 + n]);
        } else if (idx < 16384 + 8192) {
            int t2 = idx - 16384;
            int n = t2 >> 7, k = t2 & 127;
            Wt2[t2] = f2bf(W2[k * 64 + n]);
        }
    }
}

// ---- scatter edges into bucket-contiguous packed records (loc<<24 | src) ----
__global__ __launch_bounds__(256) void k_bscatter(const int* __restrict__ src,
                                                  const int* __restrict__ dst, int E, int B,
                                                  const int* __restrict__ boff,
                                                  int* __restrict__ bfill,
                                                  unsigned* __restrict__ pairs) {
    __shared__ int lc[MAXB];     // per-block bucket count, then per-bucket rank
    __shared__ int lbase[MAXB];  // global reservation base within bucket
    const int tid = threadIdx.x;
    const int e0 = blockIdx.x * 8192;
    for (int i = tid; i < MAXB; i += 256) lc[i] = 0;
    __syncthreads();
#pragma unroll
    for (int k = 0; k < 32; k++) {
        int e = e0 + k * 256 + tid;
        if (e < E) atomicAdd(&lc[dst[e] >> BSHIFT], 1);
    }
    __syncthreads();
    for (int b = tid; b < B; b += 256)
        lbase[b] = lc[b] ? atomicAdd(&bfill[b], lc[b]) : 0;
    __syncthreads();
    for (int i = tid; i < MAXB; i += 256) lc[i] = 0;  // reuse as rank
    __syncthreads();
#pragma unroll
    for (int k = 0; k < 32; k++) {
        int e = e0 + k * 256 + tid;
        if (e < E) {
            int s = src[e], d = dst[e];
            int b = d >> BSHIFT;
            int r = atomicAdd(&lc[b], 1);
            pairs[(size_t)boff[b] + lbase[b] + r] =
                ((unsigned)(d & 255) << 24) | (unsigned)s;   // src < 2^24
        }
    }
}

// ---- per-bucket CSR build (round-5 form): one block per bucket ----
__global__ __launch_bounds__(256) void k_bbuild(const unsigned* __restrict__ pairs,
                                                const int* __restrict__ boff, int N,
                                                int* __restrict__ deg,
                                                float* __restrict__ dinv,
                                                int* __restrict__ rowptr,
                                                int* __restrict__ csr_src) {
    __shared__ int ldeg[256], lex[256], lrank[256];
    const int b = blockIdx.x, tid = threadIdx.x;
    const int node0 = b << BSHIFT;
    const int base = boff[b];
    const int cnt_e = boff[b + 1] - base;
    ldeg[tid] = 0;
    __syncthreads();
    for (int e = tid; e < cnt_e; e += 256)
        atomicAdd(&ldeg[pairs[base + e] >> 24], 1);
    __syncthreads();
    int v = ldeg[tid];
    lex[tid] = v; __syncthreads();
    for (int o = 1; o < 256; o <<= 1) {
        int add = (tid >= o) ? lex[tid - o] : 0;
        __syncthreads();
        lex[tid] += add;
        __syncthreads();
    }
    int excl = lex[tid] - v;
    if (node0 + tid < N) {
        deg[node0 + tid] = v;
        dinv[node0 + tid] = rsqrtf((float)(v + 1));
        rowptr[node0 + tid] = base + excl;
    }
    __syncthreads();
    lex[tid] = excl;
    lrank[tid] = 0;
    __syncthreads();
    for (int e = tid; e < cnt_e; e += 256) {
        unsigned p = pairs[base + e];
        int loc = p >> 24;
        int r = atomicAdd(&lrank[loc], 1);
        csr_src[base + lex[loc] + r] = (int)(p & 0xFFFFFFu);
    }
}

// C[M x NC](bf16) = dinv[row] * (A[M x 128] @ Wt^T). Wt is [NC x 128] bf16.
typedef __attribute__((ext_vector_type(8))) short bf16x8;
typedef __attribute__((ext_vector_type(4))) float f32x4;

template <int NC, bool A_BF16>
__global__ __launch_bounds__(256) void k_gemm_mfma(const void* __restrict__ Av,
                                                   const unsigned short* __restrict__ Wt,
                                                   const float* __restrict__ dinv,
                                                   unsigned short* __restrict__ Out, int M) {
    constexpr int KP = 136;                 // padded k-stride
    __shared__ __align__(16) short As[64 * KP];
    __shared__ __align__(16) short Bs[NC * KP];
    const int tid = threadIdx.x;
    const int row0 = blockIdx.x * 64;

    if (A_BF16) {
        const unsigned short* A = (const unsigned short*)Av;
#pragma unroll
        for (int q = 0; q < 4; q++) {
            int f = tid + 256 * q;
            int r = f >> 4, c = (f & 15) * 8;
            uint4 v = make_uint4(0, 0, 0, 0);
            if (row0 + r < M) v = *(const uint4*)&A[(size_t)(row0 + r) * 128 + c];
            *(uint4*)&As[r * KP + c] = v;
        }
    } else {
        const float* A = (const float*)Av;
#pragma unroll
        for (int q = 0; q < 8; q++) {
            int f = tid + 256 * q;
            int r = f >> 5, c = (f & 31) * 4;
            float4 v = make_float4(0.f, 0.f, 0.f, 0.f);
            if (row0 + r < M) v = *(const float4*)&A[(size_t)(row0 + r) * 128 + c];
            ushort4 o;
            o.x = f2bf(v.x); o.y = f2bf(v.y); o.z = f2bf(v.z); o.w = f2bf(v.w);
            *(ushort4*)&As[r * KP + c] = o;
        }
    }
    for (int f = tid; f < NC * 16; f += 256) {
        int n = f >> 4, c = (f & 15) * 8;
        *(uint4*)&Bs[n * KP + c] = *(const uint4*)&Wt[n * 128 + c];
    }
    __syncthreads();

    const int wave = tid >> 6, lane = tid & 63;
    const int m = lane & 15, quad = lane >> 4;
    constexpr int CT = NC / 16;
    f32x4 acc[CT] = {};
    const short* arow = &As[(16 * wave + m) * KP + quad * 8];
    const short* brow = &Bs[m * KP + quad * 8];
#pragma unroll
    for (int k0 = 0; k0 < 128; k0 += 32) {
        bf16x8 a = *(const bf16x8*)&arow[k0];
#pragma unroll
        for (int c = 0; c < CT; c++) {
            bf16x8 b = *(const bf16x8*)&brow[(size_t)c * 16 * KP + k0];
            acc[c] = __builtin_amdgcn_mfma_f32_16x16x32_bf16(a, b, acc[c], 0, 0, 0);
        }
    }

    // row-scale by dinv and repack through LDS for coalesced bf16 stores
    float dv[4];
#pragma unroll
    for (int r = 0; r < 4; r++) {
        int row = row0 + 16 * wave + quad * 4 + r;
        dv[r] = dinv[row < M ? row : (M - 1)];
    }
    __syncthreads();
    short* Cs = As;
#pragma unroll
    for (int c = 0; c < CT; c++)
#pragma unroll
        for (int r = 0; r < 4; r++)
            Cs[(16 * wave + quad * 4 + r) * NC + 16 * c + m] = (short)f2bf(acc[c][r] * dv[r]);
    __syncthreads();
    for (int f = tid; f < 64 * NC / 8; f += 256) {
        int r = f / (NC / 8), c = (f % (NC / 8)) * 8;
        if (row0 + r < M)
            *(uint4*)&Out[(size_t)(row0 + r) * NC + c] = *(const uint4*)&Cs[r * NC + c];
    }
}

// Aggregate 128-wide pre-scaled bf16 rows: pure gather-sum, then di*acc + bias, ReLU.
__global__ __launch_bounds__(256) void k_agg128b(const int* __restrict__ csr_src,
                                                 const int* __restrict__ rowptr,
                                                 const int* __restrict__ cnt,
                                                 const float* __restrict__ dinv,
                                                 const unsigned* __restrict__ xw,
                                                 const float* __restrict__ bias,
                                                 unsigned* __restrict__ h1, int N) {
    const int lane = threadIdx.x & 63;
    const int i = (blockIdx.x * blockDim.x + threadIdx.x) >> 6;
    if (i >= N) return;
    const float di = dinv[i];
    unsigned u = xw[(size_t)i * 64 + lane];          // self row (pre-scaled by dinv[i])
    float acc0 = bf_lo(u);
    float acc1 = bf_hi(u);
    const int start = rowptr[i], cn = cnt[i];
    int j = 0;
    for (; j + 8 <= cn; j += 8) {
        int s[8]; unsigned uu[8];
#pragma unroll
        for (int k = 0; k < 8; k++) s[k] = __builtin_nontemporal_load(&csr_src[start + j + k]);
#pragma unroll
        for (int k = 0; k < 8; k++) uu[k] = xw[(size_t)s[k] * 64 + lane];
#pragma unroll
        for (int k = 0; k < 8; k++) {
            acc0 += bf_lo(uu[k]);
            acc1 += bf_hi(uu[k]);
        }
    }
    for (; j < cn; j++) {
        int s0 = __builtin_nontemporal_load(&csr_src[start + j]);
        unsigned u0 = xw[(size_t)s0 * 64 + lane];
        acc0 += bf_lo(u0); acc1 += bf_hi(u0);
    }
    float2 b = *(const float2*)&bias[2 * lane];
    float r0 = fmaxf(di * acc0 + b.x, 0.f);          // ReLU folded (layer-1 epilogue)
    float r1 = fmaxf(di * acc1 + b.y, 0.f);
    h1[(size_t)i * 64 + lane] = (unsigned)f2bf(r0) | ((unsigned)f2bf(r1) << 16);
}

// Aggregate 64-wide pre-scaled bf16 rows; half-wave per edge stream, 4-deep unroll.
// log_softmax fused into the epilogue.
__global__ __launch_bounds__(256) void k_agg64b(const int* __restrict__ csr_src,
                                                const int* __restrict__ rowptr,
                                                const int* __restrict__ cnt,
                                                const float* __restrict__ dinv,
                                                const unsigned* __restrict__ xw,
                                                const float* __restrict__ bias,
                                                float* __restrict__ out, int N) {
    const int lane = threadIdx.x & 63;
    const int i = (blockIdx.x * blockDim.x + threadIdx.x) >> 6;
    if (i >= N) return;
    const int h = lane >> 5, sl = lane & 31;
    const float di = dinv[i];
    float acc0 = 0.f, acc1 = 0.f;
    if (h == 0) {
        unsigned u = xw[(size_t)i * 32 + sl];        // self row (pre-scaled)
        acc0 = bf_lo(u);
        acc1 = bf_hi(u);
    }
    const int start = rowptr[i], cn = cnt[i];
    int e = h;
    for (; e + 6 < cn; e += 8) {          // each half: edges e, e+2, e+4, e+6
        int s[4]; unsigned uu[4];
#pragma unroll
        for (int k = 0; k < 4; k++) s[k] = __builtin_nontemporal_load(&csr_src[start + e + 2 * k]);
#pragma unroll
        for (int k = 0; k < 4; k++) uu[k] = xw[(size_t)s[k] * 32 + sl];
#pragma unroll
        for (int k = 0; k < 4; k++) {
            acc0 += bf_lo(uu[k]);
            acc1 += bf_hi(uu[k]);
        }
    }
    for (; e < cn; e += 2) {
        int s0 = __builtin_nontemporal_load(&csr_src[start + e]);
        unsigned u0 = xw[(size_t)s0 * 32 + sl];
        acc0 += bf_lo(u0); acc1 += bf_hi(u0);
    }
    acc0 += __shfl_xor(acc0, 32);         // both halves now hold full sums
    acc1 += __shfl_xor(acc1, 32);
    float2 b = *(const float2*)&bias[2 * sl];
    float v0 = di * acc0 + b.x, v1 = di * acc1 + b.y;
    float m = fmaxf(v0, v1);
#pragma unroll
    for (int o = 16; o > 0; o >>= 1) m = fmaxf(m, __shfl_xor(m, o));
    float s2 = expf(v0 - m) + expf(v1 - m);
#pragma unroll
    for (int o = 16; o > 0; o >>= 1) s2 += __shfl_xor(s2, o);
    float ls = m + logf(s2);
    if (h == 0)
        *(float2*)&out[(size_t)i * 64 + 2 * sl] = make_float2(v0 - ls, v1 - ls);
}

extern "C" void kernel_launch(void* const* d_in, const int* in_sizes, int n_in,
                              void* d_out, int out_size, void* d_ws, size_t ws_size,
                              hipStream_t stream) {
    const float* x  = (const float*)d_in[0];
    const int*   ei = (const int*)d_in[1];
    const float* W1 = (const float*)d_in[2];
    const float* b1 = (const float*)d_in[3];
    const float* W2 = (const float*)d_in[4];
    const float* b2 = (const float*)d_in[5];

    const int N = in_sizes[0] / 128;   // 100000
    const int E = in_sizes[1] / 2;     // 1600000
    const int* src = ei;
    const int* dst = ei + E;
    const int B = (N + 255) >> BSHIFT; // 391 buckets

    char* ws = (char*)d_ws;
    size_t off = 0;
    auto alloc = [&](size_t bytes) {
        void* p = ws + off;
        off += (bytes + 255) & ~(size_t)255;
        return p;
    };
    int*            bcnt    = (int*)alloc(MAXB * 4 * 2);    // bcnt + bfill adjacent
    int*            bfill   = bcnt + MAXB;
    int*            boff    = (int*)alloc((MAXB + 1) * 4);
    int*            deg     = (int*)alloc((size_t)N * 4);
    float*          dinv    = (float*)alloc((size_t)N * 4);
    int*            rowptr  = (int*)alloc((size_t)N * 4);
    int*            csr_src = (int*)alloc((size_t)E * 4);
    unsigned*       pairs   = (unsigned*)alloc((size_t)E * 4);
    unsigned short* Wt1     = (unsigned short*)alloc(128 * 128 * 2);
    unsigned short* Wt2     = (unsigned short*)alloc(64 * 128 * 2);
    unsigned short* xw1     = (unsigned short*)alloc((size_t)N * 128 * 2);  // bf16; reused as hw2
    unsigned short* h1      = (unsigned short*)alloc((size_t)N * 128 * 2);  // bf16
    unsigned short* hw2     = xw1;
    float*          out     = (float*)d_out;

    hipMemsetAsync(bcnt, 0, MAXB * 4 * 2, stream);

    // CSR build (bucketed) + weight cast
    k_bcount<<<512, THREADS, 0, stream>>>(dst, E, B, bcnt);
    k_bscan<<<49, 512, 0, stream>>>(bcnt, B, boff, W1, W2, Wt1, Wt2);
    k_bscatter<<<(E + 8191) / 8192, THREADS, 0, stream>>>(src, dst, E, B, boff, bfill, pairs);
    k_bbuild<<<B, THREADS, 0, stream>>>(pairs, boff, N, deg, dinv, rowptr, csr_src);

    // Layer 1 (table pre-scaled by dinv[row] in the GEMM epilogue)
    k_gemm_mfma<128, false><<<(N + 63) / 64, THREADS, 0, stream>>>(x, Wt1, dinv, xw1, N);
    k_agg128b<<<(N * 64 + THREADS - 1) / THREADS, THREADS, 0, stream>>>(
        csr_src, rowptr, deg, dinv, (const unsigned*)xw1, b1, (unsigned*)h1, N);

    // Layer 2 (+ fused log_softmax)
    k_gemm_mfma<64, true><<<(N + 63) / 64, THREADS, 0, stream>>>(h1, Wt2, dinv, hw2, N);
    k_agg64b<<<(N * 64 + THREADS - 1) / THREADS, THREADS, 0, stream>>>(
        csr_src, rowptr, deg, dinv, (const unsigned*)hw2, b2, out, N);
}